// Round 15
// baseline (59.887 us; speedup 1.0000x reference)
//
#include <hip/hip_runtime.h>
#include <math.h>

#define DH 15
#define NNODES 64           // Chebyshev-Lobatto nodes, degree 63
#define M_DEG  63

typedef float v2f __attribute__((ext_vector_type(2)));

// ---- stable tanh + derivative factors -------------------------------------
__device__ __forceinline__ void tanh_fs(float u0, float& t, float& s,
                                        float& f2, float& f3, float& f4) {
    float e = __builtin_amdgcn_exp2f(u0 * 2.885390081777927f); // exp(2*u0)
    float r = __builtin_amdgcn_rcpf(1.0f + e);
    t = 1.0f - 2.0f * r;
    s = 4.0f * r * (1.0f - r);
    f2 = -2.0f * t * s;
    f3 = s * (4.0f * t * t - 2.0f * s);
    f4 = 8.0f * t * s * (2.0f * s - t * t);
}

__device__ __forceinline__ void tanh_jet(float u0, float u1, float u2,
                                         float u3, float u4, float h[5]) {
    float t, s, f2, f3, f4;
    tanh_fs(u0, t, s, f2, f3, f4);
    float u1s = u1 * u1;
    h[0] = t;
    h[1] = s * u1;
    h[2] = f2 * u1s + s * u2;
    h[3] = f3 * u1s * u1 + 3.0f * f2 * u1 * u2 + s * u3;
    h[4] = f4 * u1s * u1s + 6.0f * f3 * u1s * u2
         + f2 * (3.0f * u2 * u2 + 4.0f * u1 * u3) + s * u4;
}

// ---- helper: grid-stride constant fill of one [N] region --------------------
__device__ __forceinline__ void fill_region(float* __restrict__ p, float c,
                                            size_t n, size_t tid, size_t stride) {
    size_t head = ((16 - ((size_t)p & 15)) & 15) >> 2;  // floats to 16B align
    if (head > n) head = n;
    if (tid < head) p[tid] = c;
    size_t n4 = (n - head) >> 2;
    float4* p4 = reinterpret_cast<float4*>(p + head);
    float4 cv = {c, c, c, c};
    for (size_t i = tid; i < n4; i += stride) p4[i] = cv;
    size_t t = head + (n4 << 2) + tid;
    if (t < n) p[t] = c;
}

// ---- single kernel with software grid barrier -------------------------------
// Phase 1: x-prefetch; redundant 4-wave node eval + DCT (block-local bc, C);
//   BC fills (32 MB) issued before Clenshaw; Clenshaw; partials write.
// Software barrier: device-scope atomic ticket + acquire-poll (all 512 blocks
//   co-resident at 2 blocks/CU: 20 KB LDS, 84 VGPR -> no deadlock). Counter is
//   reset each call by a captured hipMemsetAsync.
// Phase 2: every block redundantly reduces partials in fixed order
//   (deterministic, identical), fills region 0 with the loss.
__global__ void __launch_bounds__(256)
pinn_all(const float* __restrict__ x,
         const float* __restrict__ W1, const float* __restrict__ b1,
         const float* __restrict__ W2, const float* __restrict__ b2,
         const float* __restrict__ W3, const float* __restrict__ b3,
         const float* __restrict__ W4, const float* __restrict__ b4,
         float* __restrict__ out, double* __restrict__ partials,
         unsigned int* __restrict__ counter, int N, int NB) {
    __shared__ float hs[DH][5][NNODES];
    __shared__ alignas(16) float rsh[NNODES];
    __shared__ float C_lds[NNODES];
    __shared__ float bc_lds[10];
    __shared__ double red[4];
    const int tid  = threadIdx.x;
    const int lane = tid & 63;           // node index
    const int wq   = tid >> 6;           // j-quad (wave-uniform)

    // ---- prefetch this thread's x (≤4 float4) before the nodes phase -------
    int i0 = blockIdx.x * blockDim.x + tid;
    int gsz = gridDim.x * blockDim.x;
    int n4 = N >> 2;
    const float4* x4 = reinterpret_cast<const float4*>(x);
    float4 px[4];
    bool pv[4];
#pragma unroll
    for (int m = 0; m < 4; ++m) {
        int ii = i0 + m * gsz;
        pv[m] = (ii < n4);
        px[m] = pv[m] ? x4[ii] : float4{0.f, 0.f, 0.f, 0.f};
    }

    // ===================== nodes phase (every block) =========================
    float xv;
    if (lane == 0)           xv = 1.0f;
    else if (lane == M_DEG)  xv = 0.0f;
    else xv = 0.5f + 0.5f * __builtin_amdgcn_cosf((float)lane * (1.0f / 126.0f));

#pragma unroll
    for (int jj = 0; jj < 4; ++jj) {     // layer 1: 4 neurons per wave
        int j = wq * 4 + jj;
        if (j < DH) {
            float w = W1[j];
            float t, s, f2, f3, f4;
            tanh_fs(fmaf(xv, w, b1[j]), t, s, f2, f3, f4);
            float w2 = w * w;
            hs[j][0][lane] = t;
            hs[j][1][lane] = s * w;
            hs[j][2][lane] = f2 * w2;
            hs[j][3][lane] = f3 * w2 * w;
            hs[j][4][lane] = f4 * w2 * w2;
        }
    }
    __syncthreads();

    const float* Ws[2] = {W2, W3};       // layers 2 and 3
    const float* Bs[2] = {b2, b3};
#pragma unroll
    for (int L = 0; L < 2; ++L) {
        const float* W = Ws[L];
        const float* B = Bs[L];
        float u[4][5];
#pragma unroll
        for (int jj = 0; jj < 4; ++jj)
#pragma unroll
            for (int c = 0; c < 5; ++c) u[jj][c] = 0.f;
#pragma unroll
        for (int k = 0; k < DH; ++k) {
            float g0 = hs[k][0][lane], g1 = hs[k][1][lane], g2 = hs[k][2][lane],
                  g3 = hs[k][3][lane], g4 = hs[k][4][lane];
#pragma unroll
            for (int jj = 0; jj < 4; ++jj) {
                int j = wq * 4 + jj;
                float w = (j < DH) ? W[k * DH + j] : 0.f;
                u[jj][0] = fmaf(g0, w, u[jj][0]);
                u[jj][1] = fmaf(g1, w, u[jj][1]);
                u[jj][2] = fmaf(g2, w, u[jj][2]);
                u[jj][3] = fmaf(g3, w, u[jj][3]);
                u[jj][4] = fmaf(g4, w, u[jj][4]);
            }
        }
        __syncthreads();
#pragma unroll
        for (int jj = 0; jj < 4; ++jj) {
            int j = wq * 4 + jj;
            if (j < DH) {
                float hj[5];
                tanh_jet(u[jj][0] + B[j], u[jj][1], u[jj][2], u[jj][3],
                         u[jj][4], hj);
                hs[j][0][lane] = hj[0]; hs[j][1][lane] = hj[1];
                hs[j][2][lane] = hj[2]; hs[j][3][lane] = hj[3];
                hs[j][4][lane] = hj[4];
            }
        }
        __syncthreads();
    }

    // output layer + residual + DCT: wave 0 only
    if (wq == 0) {
        float o0 = b4[0], o1 = 0.f, o2 = 0.f, o3 = 0.f, o4 = 0.f;
#pragma unroll
        for (int k = 0; k < DH; ++k) {
            float w = W4[k];
            o0 = fmaf(hs[k][0][lane], w, o0);
            o1 = fmaf(hs[k][1][lane], w, o1);
            o2 = fmaf(hs[k][2][lane], w, o2);
            o3 = fmaf(hs[k][3][lane], w, o3);
            o4 = fmaf(hs[k][4][lane], w, o4);
        }
        rsh[lane] = ((lane == 0 || lane == M_DEG) ? 0.5f : 1.0f) * (o4 + 1.0f);
        if (lane == M_DEG) {                  // x = 0 (left)
            bc_lds[0] = o0; bc_lds[1] = o1; bc_lds[2] = o2;
            bc_lds[3] = o3; bc_lds[4] = o4;
        }
        if (lane == 0) {                      // x = 1 (right)
            bc_lds[5] = o0; bc_lds[6] = o1; bc_lds[7] = o2;
            bc_lds[8] = o3; bc_lds[9] = o4;
        }
        __builtin_amdgcn_s_waitcnt(0);  // wave-level fence on rsh

        // DCT-I, v_cos in revolutions, phase accumulation w/ conditional wrap
        float rs[NNODES];
#pragma unroll
        for (int i = 0; i < NNODES / 4; ++i) {
            float4 q = *reinterpret_cast<const float4*>(&rsh[4 * i]);
            rs[4*i] = q.x; rs[4*i+1] = q.y; rs[4*i+2] = q.z; rs[4*i+3] = q.w;
        }
        float kstep = (float)lane * (1.0f / 126.0f);
        float ph = 0.f;
        float a0 = 0.f, a1 = 0.f, a2 = 0.f, a3 = 0.f;
#pragma unroll
        for (int jj = 0; jj < NNODES; ++jj) {
            float cv = __builtin_amdgcn_cosf(ph);
            ph += kstep;
            ph = (ph >= 1.0f) ? ph - 1.0f : ph;
            float v = rs[jj] * cv;
            if ((jj & 3) == 0) a0 += v;
            else if ((jj & 3) == 1) a1 += v;
            else if ((jj & 3) == 2) a2 += v;
            else a3 += v;
        }
        float e = ((a0 + a1) + (a2 + a3)) * (2.0f / 63.0f);
        if (lane == 0 || lane == M_DEG) e *= 0.5f;
        C_lds[lane] = e;
    }
    __syncthreads();

    // ===================== BC fills (32 MB), before Clenshaw =================
    float lbw  = bc_lds[0] * bc_lds[0];
    float lbwx = bc_lds[1] * bc_lds[1];
    float rbM  = bc_lds[7] * bc_lds[7];
    float rbw  = bc_lds[5] * bc_lds[5];
    size_t gtid = (size_t)i0;
    size_t gstride = (size_t)gsz;
    fill_region(out + (size_t)1 * N + 1, lbw,  (size_t)N, gtid, gstride);
    fill_region(out + (size_t)2 * N + 1, lbwx, (size_t)N, gtid, gstride);
    fill_region(out + (size_t)3 * N + 1, rbM,  (size_t)N, gtid, gstride);
    fill_region(out + (size_t)4 * N + 1, rbw,  (size_t)N, gtid, gstride);

    // ===================== per-point Clenshaw ===============================
    float e[NNODES];
#pragma unroll
    for (int k = 0; k < NNODES; ++k) {
        int bits = __builtin_amdgcn_readfirstlane(__float_as_int(C_lds[k]));
        e[k] = __int_as_float(bits);
    }

    v2f accA = {0.f, 0.f}, accB = {0.f, 0.f};
#pragma unroll
    for (int m = 0; m < 4; ++m) {
        if (pv[m]) {
            float4 xv4 = px[m];
            v2f tA = {2.f * xv4.x - 1.f, 2.f * xv4.y - 1.f};
            v2f tB = {2.f * xv4.z - 1.f, 2.f * xv4.w - 1.f};
            v2f t2A = tA + tA, t2B = tB + tB;
            v2f b0A = {0.f, 0.f}, b1A = {0.f, 0.f};
            v2f b0B = {0.f, 0.f}, b1B = {0.f, 0.f};
#pragma unroll
            for (int k = M_DEG; k >= 1; --k) {
                v2f ek = {e[k], e[k]};
                v2f bnA = __builtin_elementwise_fma(t2A, b0A, ek) - b1A;
                b1A = b0A; b0A = bnA;
                v2f bnB = __builtin_elementwise_fma(t2B, b0B, ek) - b1B;
                b1B = b0B; b0B = bnB;
            }
            v2f e0 = {e[0], e[0]};
            v2f rA = __builtin_elementwise_fma(tA, b0A, e0) - b1A;
            v2f rB = __builtin_elementwise_fma(tB, b0B, e0) - b1B;
            accA = __builtin_elementwise_fma(rA, rA, accA);
            accB = __builtin_elementwise_fma(rB, rB, accB);
        }
    }
    for (int i = i0 + 4 * gsz; i < n4; i += gsz) {  // if grid was shrunk
        float4 xv4 = x4[i];
        v2f tA = {2.f * xv4.x - 1.f, 2.f * xv4.y - 1.f};
        v2f tB = {2.f * xv4.z - 1.f, 2.f * xv4.w - 1.f};
        v2f t2A = tA + tA, t2B = tB + tB;
        v2f b0A = {0.f, 0.f}, b1A = {0.f, 0.f};
        v2f b0B = {0.f, 0.f}, b1B = {0.f, 0.f};
#pragma unroll
        for (int k = M_DEG; k >= 1; --k) {
            v2f ek = {e[k], e[k]};
            v2f bnA = __builtin_elementwise_fma(t2A, b0A, ek) - b1A;
            b1A = b0A; b0A = bnA;
            v2f bnB = __builtin_elementwise_fma(t2B, b0B, ek) - b1B;
            b1B = b0B; b0B = bnB;
        }
        v2f e0 = {e[0], e[0]};
        v2f rA = __builtin_elementwise_fma(tA, b0A, e0) - b1A;
        v2f rB = __builtin_elementwise_fma(tB, b0B, e0) - b1B;
        accA = __builtin_elementwise_fma(rA, rA, accA);
        accB = __builtin_elementwise_fma(rB, rB, accB);
    }
    float accs = (accA.x + accA.y) + (accB.x + accB.y);
    for (int i = (n4 << 2) + i0; i < N; i += gsz) {   // tail (N % 4)
        float t = 2.f * x[i] - 1.f, t2 = t + t;
        float b0 = 0.f, b1 = 0.f;
#pragma unroll
        for (int k = M_DEG; k >= 1; --k) {
            float bn = fmaf(t2, b0, e[k]) - b1;
            b1 = b0; b0 = bn;
        }
        float r = fmaf(t, b0, e[0]) - b1;
        accs = fmaf(r, r, accs);
    }

    double a = (double)accs;
#pragma unroll
    for (int off = 32; off > 0; off >>= 1) a += __shfl_down(a, off, 64);
    if ((tid & 63) == 0) red[tid >> 6] = a;
    __syncthreads();
    if (tid == 0) {
        partials[blockIdx.x] = red[0] + red[1] + red[2] + red[3];
        __threadfence();                          // publish partial device-wide
        atomicAdd(counter, 1u);                   // device-scope by default
        // acquire-poll until all blocks arrived (all co-resident -> no deadlock)
        while (__hip_atomic_load(counter, __ATOMIC_ACQUIRE,
                                 __HIP_MEMORY_SCOPE_AGENT) < (unsigned)NB) {
            __builtin_amdgcn_s_sleep(8);
        }
    }
    __syncthreads();                              // release whole block

    // ===================== phase 2: loss fill ===============================
    double a2 = 0.0;
    for (int i = tid; i < NB; i += 256) a2 += partials[i];
#pragma unroll
    for (int off = 32; off > 0; off >>= 1) a2 += __shfl_down(a2, off, 64);
    if ((tid & 63) == 0) red[tid >> 6] = a2;
    __syncthreads();
    double total = red[0] + red[1] + red[2] + red[3];  // identical per block
    float pdef = (float)(total / (double)N);
    float loss = pdef + lbw + lbwx + rbM + rbw;        // reference add order

    fill_region(out, loss, (size_t)N, gtid, gstride);
    if (blockIdx.x == 0 && tid == 0) out[N] = pdef;    // pde_loss scalar
}

extern "C" void kernel_launch(void* const* d_in, const int* in_sizes, int n_in,
                              void* d_out, int out_size, void* d_ws, size_t ws_size,
                              hipStream_t stream) {
    const float* x  = (const float*)d_in[0];
    const float* W1 = (const float*)d_in[1];
    const float* b1 = (const float*)d_in[2];
    const float* W2 = (const float*)d_in[3];
    const float* b2 = (const float*)d_in[4];
    const float* W3 = (const float*)d_in[5];
    const float* b3 = (const float*)d_in[6];
    const float* W4 = (const float*)d_in[7];
    const float* b4 = (const float*)d_in[8];
    float* out = (float*)d_out;
    int N = in_sizes[0];

    // ws layout: counter @0 (reset each call) | partials @1024B
    unsigned int* counter = (unsigned int*)d_ws;
    double* partials = (double*)((char*)d_ws + 1024);

    int NB = 512;   // 2 blocks/CU -> all blocks co-resident (barrier-safe)
    size_t need = 1024 + (size_t)NB * 8;
    if (ws_size < need) {
        NB = (int)((ws_size > 1024 + 8) ? (ws_size - 1024) / 8 : 1);
        if (NB < 1) NB = 1;
        if (NB > 512) NB = 512;
    }

    hipMemsetAsync(counter, 0, 128, stream);      // captured as a memset node
    hipLaunchKernelGGL(pinn_all, dim3(NB), dim3(256), 0, stream,
                       x, W1, b1, W2, b2, W3, b3, W4, b4,
                       out, partials, counter, N, NB);
}

// Round 16
// 28.292 us; speedup vs baseline: 2.1167x; 2.1167x over previous
//
#include <hip/hip_runtime.h>
#include <math.h>

#define DH 15
#define NNODES 64           // Chebyshev-Lobatto nodes, degree 63
#define M_DEG  63

typedef float v2f __attribute__((ext_vector_type(2)));

// ---- stable tanh + derivative factors -------------------------------------
__device__ __forceinline__ void tanh_fs(float u0, float& t, float& s,
                                        float& f2, float& f3, float& f4) {
    float e = __builtin_amdgcn_exp2f(u0 * 2.885390081777927f); // exp(2*u0)
    float r = __builtin_amdgcn_rcpf(1.0f + e);
    t = 1.0f - 2.0f * r;
    s = 4.0f * r * (1.0f - r);
    f2 = -2.0f * t * s;
    f3 = s * (4.0f * t * t - 2.0f * s);
    f4 = 8.0f * t * s * (2.0f * s - t * t);
}

__device__ __forceinline__ void tanh_jet(float u0, float u1, float u2,
                                         float u3, float u4, float h[5]) {
    float t, s, f2, f3, f4;
    tanh_fs(u0, t, s, f2, f3, f4);
    float u1s = u1 * u1;
    h[0] = t;
    h[1] = s * u1;
    h[2] = f2 * u1s + s * u2;
    h[3] = f3 * u1s * u1 + 3.0f * f2 * u1 * u2 + s * u3;
    h[4] = f4 * u1s * u1s + 6.0f * f3 * u1s * u2
         + f2 * (3.0f * u2 * u2 + 4.0f * u1 * u3) + s * u4;
}

// ---- helper: grid-stride constant fill of one [N] region --------------------
__device__ __forceinline__ void fill_region(float* __restrict__ p, float c,
                                            size_t n, size_t tid, size_t stride) {
    size_t head = ((16 - ((size_t)p & 15)) & 15) >> 2;  // floats to 16B align
    if (head > n) head = n;
    if (tid < head) p[tid] = c;
    size_t n4 = (n - head) >> 2;
    float4* p4 = reinterpret_cast<float4*>(p + head);
    float4 cv = {c, c, c, c};
    for (size_t i = tid; i < n4; i += stride) p4[i] = cv;
    size_t t = head + (n4 << 2) + tid;
    if (t < n) p[t] = c;
}

// ---- K1: x-prefetch -> redundant node eval + DCT -> BC fills -> Clenshaw ----
// BC fills (32 MB) are issued between the nodes phase and the Clenshaw loop so
// their store drain overlaps the remaining VALU work.
__global__ void __launch_bounds__(256)
pinn_pde(const float* __restrict__ x,
         const float* __restrict__ W1, const float* __restrict__ b1,
         const float* __restrict__ W2, const float* __restrict__ b2,
         const float* __restrict__ W3, const float* __restrict__ b3,
         const float* __restrict__ W4, const float* __restrict__ b4,
         float* __restrict__ out, float* __restrict__ bcg,
         double* __restrict__ partials, int N) {
    __shared__ float hs[DH][5][NNODES];
    __shared__ alignas(16) float rsh[NNODES];
    __shared__ float C_lds[NNODES];
    __shared__ float bc_lds[10];
    const int tid  = threadIdx.x;
    const int lane = tid & 63;           // node index
    const int wq   = tid >> 6;           // j-quad (wave-uniform)

    // ---- prefetch this thread's x (≤4 float4) before the nodes phase -------
    int i0 = blockIdx.x * blockDim.x + tid;
    int gsz = gridDim.x * blockDim.x;
    int n4 = N >> 2;
    const float4* x4 = reinterpret_cast<const float4*>(x);
    float4 px[4];
    bool pv[4];
#pragma unroll
    for (int m = 0; m < 4; ++m) {
        int ii = i0 + m * gsz;
        pv[m] = (ii < n4);
        px[m] = pv[m] ? x4[ii] : float4{0.f, 0.f, 0.f, 0.f};
    }

    // ===================== nodes phase (every block) =========================
    float xv;
    if (lane == 0)           xv = 1.0f;
    else if (lane == M_DEG)  xv = 0.0f;
    else xv = 0.5f + 0.5f * __builtin_amdgcn_cosf((float)lane * (1.0f / 126.0f));

#pragma unroll
    for (int jj = 0; jj < 4; ++jj) {     // layer 1: 4 neurons per wave
        int j = wq * 4 + jj;
        if (j < DH) {
            float w = W1[j];
            float t, s, f2, f3, f4;
            tanh_fs(fmaf(xv, w, b1[j]), t, s, f2, f3, f4);
            float w2 = w * w;
            hs[j][0][lane] = t;
            hs[j][1][lane] = s * w;
            hs[j][2][lane] = f2 * w2;
            hs[j][3][lane] = f3 * w2 * w;
            hs[j][4][lane] = f4 * w2 * w2;
        }
    }
    __syncthreads();

    const float* Ws[2] = {W2, W3};       // layers 2 and 3
    const float* Bs[2] = {b2, b3};
#pragma unroll
    for (int L = 0; L < 2; ++L) {
        const float* W = Ws[L];
        const float* B = Bs[L];
        float u[4][5];
#pragma unroll
        for (int jj = 0; jj < 4; ++jj)
#pragma unroll
            for (int c = 0; c < 5; ++c) u[jj][c] = 0.f;
#pragma unroll
        for (int k = 0; k < DH; ++k) {
            float g0 = hs[k][0][lane], g1 = hs[k][1][lane], g2 = hs[k][2][lane],
                  g3 = hs[k][3][lane], g4 = hs[k][4][lane];
#pragma unroll
            for (int jj = 0; jj < 4; ++jj) {
                int j = wq * 4 + jj;
                float w = (j < DH) ? W[k * DH + j] : 0.f;
                u[jj][0] = fmaf(g0, w, u[jj][0]);
                u[jj][1] = fmaf(g1, w, u[jj][1]);
                u[jj][2] = fmaf(g2, w, u[jj][2]);
                u[jj][3] = fmaf(g3, w, u[jj][3]);
                u[jj][4] = fmaf(g4, w, u[jj][4]);
            }
        }
        __syncthreads();
#pragma unroll
        for (int jj = 0; jj < 4; ++jj) {
            int j = wq * 4 + jj;
            if (j < DH) {
                float hj[5];
                tanh_jet(u[jj][0] + B[j], u[jj][1], u[jj][2], u[jj][3],
                         u[jj][4], hj);
                hs[j][0][lane] = hj[0]; hs[j][1][lane] = hj[1];
                hs[j][2][lane] = hj[2]; hs[j][3][lane] = hj[3];
                hs[j][4][lane] = hj[4];
            }
        }
        __syncthreads();
    }

    // output layer + residual + DCT: wave 0 only
    if (wq == 0) {
        float o0 = b4[0], o1 = 0.f, o2 = 0.f, o3 = 0.f, o4 = 0.f;
#pragma unroll
        for (int k = 0; k < DH; ++k) {
            float w = W4[k];
            o0 = fmaf(hs[k][0][lane], w, o0);
            o1 = fmaf(hs[k][1][lane], w, o1);
            o2 = fmaf(hs[k][2][lane], w, o2);
            o3 = fmaf(hs[k][3][lane], w, o3);
            o4 = fmaf(hs[k][4][lane], w, o4);
        }
        rsh[lane] = ((lane == 0 || lane == M_DEG) ? 0.5f : 1.0f) * (o4 + 1.0f);
        if (lane == M_DEG) {                  // x = 0 (left)
            bc_lds[0] = o0; bc_lds[1] = o1; bc_lds[2] = o2;
            bc_lds[3] = o3; bc_lds[4] = o4;
            if (blockIdx.x == 0) {
                bcg[0] = o0; bcg[1] = o1; bcg[2] = o2; bcg[3] = o3; bcg[4] = o4;
            }
        }
        if (lane == 0) {                      // x = 1 (right)
            bc_lds[5] = o0; bc_lds[6] = o1; bc_lds[7] = o2;
            bc_lds[8] = o3; bc_lds[9] = o4;
            if (blockIdx.x == 0) {
                bcg[5] = o0; bcg[6] = o1; bcg[7] = o2; bcg[8] = o3; bcg[9] = o4;
            }
        }
        __builtin_amdgcn_s_waitcnt(0);  // wave-level fence on rsh

        // DCT-I, v_cos in revolutions, phase accumulation w/ conditional wrap
        float rs[NNODES];
#pragma unroll
        for (int i = 0; i < NNODES / 4; ++i) {
            float4 q = *reinterpret_cast<const float4*>(&rsh[4 * i]);
            rs[4*i] = q.x; rs[4*i+1] = q.y; rs[4*i+2] = q.z; rs[4*i+3] = q.w;
        }
        float kstep = (float)lane * (1.0f / 126.0f);
        float ph = 0.f;
        float a0 = 0.f, a1 = 0.f, a2 = 0.f, a3 = 0.f;
#pragma unroll
        for (int jj = 0; jj < NNODES; ++jj) {
            float cv = __builtin_amdgcn_cosf(ph);
            ph += kstep;
            ph = (ph >= 1.0f) ? ph - 1.0f : ph;
            float v = rs[jj] * cv;
            if ((jj & 3) == 0) a0 += v;
            else if ((jj & 3) == 1) a1 += v;
            else if ((jj & 3) == 2) a2 += v;
            else a3 += v;
        }
        float e = ((a0 + a1) + (a2 + a3)) * (2.0f / 63.0f);
        if (lane == 0 || lane == M_DEG) e *= 0.5f;
        C_lds[lane] = e;
    }
    __syncthreads();

    // ===================== BC fills (32 MB), before Clenshaw =================
    float lbw  = bc_lds[0] * bc_lds[0];
    float lbwx = bc_lds[1] * bc_lds[1];
    float rbM  = bc_lds[7] * bc_lds[7];
    float rbw  = bc_lds[5] * bc_lds[5];
    size_t gtid = (size_t)i0;
    size_t gstride = (size_t)gsz;
    fill_region(out + (size_t)1 * N + 1, lbw,  (size_t)N, gtid, gstride);
    fill_region(out + (size_t)2 * N + 1, lbwx, (size_t)N, gtid, gstride);
    fill_region(out + (size_t)3 * N + 1, rbM,  (size_t)N, gtid, gstride);
    fill_region(out + (size_t)4 * N + 1, rbw,  (size_t)N, gtid, gstride);

    // ===================== per-point Clenshaw ===============================
    float e[NNODES];
#pragma unroll
    for (int k = 0; k < NNODES; ++k) {
        int bits = __builtin_amdgcn_readfirstlane(__float_as_int(C_lds[k]));
        e[k] = __int_as_float(bits);
    }

    v2f accA = {0.f, 0.f}, accB = {0.f, 0.f};
#pragma unroll
    for (int m = 0; m < 4; ++m) {
        if (pv[m]) {
            float4 xv4 = px[m];
            v2f tA = {2.f * xv4.x - 1.f, 2.f * xv4.y - 1.f};
            v2f tB = {2.f * xv4.z - 1.f, 2.f * xv4.w - 1.f};
            v2f t2A = tA + tA, t2B = tB + tB;
            v2f b0A = {0.f, 0.f}, b1A = {0.f, 0.f};
            v2f b0B = {0.f, 0.f}, b1B = {0.f, 0.f};
#pragma unroll
            for (int k = M_DEG; k >= 1; --k) {
                v2f ek = {e[k], e[k]};
                v2f bnA = __builtin_elementwise_fma(t2A, b0A, ek) - b1A;
                b1A = b0A; b0A = bnA;
                v2f bnB = __builtin_elementwise_fma(t2B, b0B, ek) - b1B;
                b1B = b0B; b0B = bnB;
            }
            v2f e0 = {e[0], e[0]};
            v2f rA = __builtin_elementwise_fma(tA, b0A, e0) - b1A;
            v2f rB = __builtin_elementwise_fma(tB, b0B, e0) - b1B;
            accA = __builtin_elementwise_fma(rA, rA, accA);
            accB = __builtin_elementwise_fma(rB, rB, accB);
        }
    }
    for (int i = i0 + 4 * gsz; i < n4; i += gsz) {  // if grid was shrunk
        float4 xv4 = x4[i];
        v2f tA = {2.f * xv4.x - 1.f, 2.f * xv4.y - 1.f};
        v2f tB = {2.f * xv4.z - 1.f, 2.f * xv4.w - 1.f};
        v2f t2A = tA + tA, t2B = tB + tB;
        v2f b0A = {0.f, 0.f}, b1A = {0.f, 0.f};
        v2f b0B = {0.f, 0.f}, b1B = {0.f, 0.f};
#pragma unroll
        for (int k = M_DEG; k >= 1; --k) {
            v2f ek = {e[k], e[k]};
            v2f bnA = __builtin_elementwise_fma(t2A, b0A, ek) - b1A;
            b1A = b0A; b0A = bnA;
            v2f bnB = __builtin_elementwise_fma(t2B, b0B, ek) - b1B;
            b1B = b0B; b0B = bnB;
        }
        v2f e0 = {e[0], e[0]};
        v2f rA = __builtin_elementwise_fma(tA, b0A, e0) - b1A;
        v2f rB = __builtin_elementwise_fma(tB, b0B, e0) - b1B;
        accA = __builtin_elementwise_fma(rA, rA, accA);
        accB = __builtin_elementwise_fma(rB, rB, accB);
    }
    float accs = (accA.x + accA.y) + (accB.x + accB.y);
    for (int i = (n4 << 2) + i0; i < N; i += gsz) {   // tail (N % 4)
        float t = 2.f * x[i] - 1.f, t2 = t + t;
        float b0 = 0.f, b1 = 0.f;
#pragma unroll
        for (int k = M_DEG; k >= 1; --k) {
            float bn = fmaf(t2, b0, e[k]) - b1;
            b1 = b0; b0 = bn;
        }
        float r = fmaf(t, b0, e[0]) - b1;
        accs = fmaf(r, r, accs);
    }

    double a = (double)accs;
#pragma unroll
    for (int off = 32; off > 0; off >>= 1) a += __shfl_down(a, off, 64);
    __shared__ double red[4];
    if ((tid & 63) == 0) red[tid >> 6] = a;
    __syncthreads();
    if (tid == 0) partials[blockIdx.x] = red[0] + red[1] + red[2] + red[3];
}

// ---- K2: minimal — fixed-order reduce + 8 MB loss fill + scalar -------------
__global__ void __launch_bounds__(256)
pinn_out(const double* __restrict__ partials, int nparts,
         const float* __restrict__ bc, float* __restrict__ out, int N) {
    int tid = threadIdx.x;
    float c0 = bc[0], c1 = bc[1], c7 = bc[7], c5 = bc[5];  // uniform -> SGPR
    float lbw  = c0 * c0;
    float lbwx = c1 * c1;
    float rbM  = c7 * c7;
    float rbw  = c5 * c5;

    // redundant fixed-order reduce (identical, deterministic in every block)
    double a = 0.0;
    for (int i = tid; i < nparts; i += 256) a += partials[i];
#pragma unroll
    for (int off = 32; off > 0; off >>= 1) a += __shfl_down(a, off, 64);
    __shared__ double red[4];
    if ((tid & 63) == 0) red[tid >> 6] = a;
    __syncthreads();
    double total = red[0] + red[1] + red[2] + red[3];
    float pdef = (float)(total / (double)N);
    float loss = pdef + lbw + lbwx + rbM + rbw;   // reference add order

    size_t gtid = (size_t)blockIdx.x * blockDim.x + tid;
    size_t gstride = (size_t)gridDim.x * blockDim.x;
    fill_region(out, loss, (size_t)N, gtid, gstride);
    if (blockIdx.x == 0 && tid == 0) out[N] = pdef;   // pde_loss scalar
}

extern "C" void kernel_launch(void* const* d_in, const int* in_sizes, int n_in,
                              void* d_out, int out_size, void* d_ws, size_t ws_size,
                              hipStream_t stream) {
    const float* x  = (const float*)d_in[0];
    const float* W1 = (const float*)d_in[1];
    const float* b1 = (const float*)d_in[2];
    const float* W2 = (const float*)d_in[3];
    const float* b2 = (const float*)d_in[4];
    const float* W3 = (const float*)d_in[5];
    const float* b3 = (const float*)d_in[6];
    const float* W4 = (const float*)d_in[7];
    const float* b4 = (const float*)d_in[8];
    float* out = (float*)d_out;
    int N = in_sizes[0];

    // ws layout: bc[10] @256B | partials @1024B
    float*  bc       = (float*)((char*)d_ws + 256);
    double* partials = (double*)((char*)d_ws + 1024);

    int NB = 512;
    size_t need = 1024 + (size_t)NB * 8;
    if (ws_size < need) {
        NB = (int)((ws_size > 1024 + 8) ? (ws_size - 1024) / 8 : 1);
        if (NB < 1) NB = 1;
        if (NB > 512) NB = 512;
    }

    hipLaunchKernelGGL(pinn_pde, dim3(NB), dim3(256), 0, stream,
                       x, W1, b1, W2, b2, W3, b3, W4, b4, out, bc, partials, N);
    hipLaunchKernelGGL(pinn_out, dim3(512), dim3(256), 0, stream,
                       partials, NB, bc, out, N);
}